// Round 2
// baseline (360.366 us; speedup 1.0000x reference)
//
#include <hip/hip_runtime.h>
#include <hip/hip_bf16.h>

#define LSEQ 512
#define EDIM 64
#define DDIM 300

__device__ __forceinline__ float wave_sum64(float v) {
  #pragma unroll
  for (int m = 32; m >= 1; m >>= 1) v += __shfl_xor(v, m, 64);
  return v;
}
__device__ __forceinline__ float wave_max64(float v) {
  #pragma unroll
  for (int m = 32; m >= 1; m >>= 1) v = fmaxf(v, __shfl_xor(v, m, 64));
  return v;
}

// ew(b,i,j) = sum_h relu(dot(emb[b,i,j,:], W_map[:,h])) * w_ew[h]
// W_map accesses are wave-uniform -> scalar loads (SGPR operands in the FMAs).
__device__ __forceinline__ float edge_score(const float* __restrict__ ep,
                                            const float* __restrict__ Wmap,
                                            const float* __restrict__ wew) {
  float s[64];
  #pragma unroll
  for (int h = 0; h < 64; ++h) s[h] = 0.f;
  #pragma unroll 4
  for (int e4 = 0; e4 < 16; ++e4) {
    const float4 v = reinterpret_cast<const float4*>(ep)[e4];
    const float* wr = Wmap + (e4 << 8);  // 4 consecutive rows of W_map
    #pragma unroll
    for (int h = 0; h < 64; ++h) s[h] = fmaf(v.x, wr[h], s[h]);
    #pragma unroll
    for (int h = 0; h < 64; ++h) s[h] = fmaf(v.y, wr[64 + h], s[h]);
    #pragma unroll
    for (int h = 0; h < 64; ++h) s[h] = fmaf(v.z, wr[128 + h], s[h]);
    #pragma unroll
    for (int h = 0; h < 64; ++h) s[h] = fmaf(v.w, wr[192 + h], s[h]);
  }
  float acc = 0.f;
  #pragma unroll
  for (int h = 0; h < 64; ++h) acc = fmaf(fmaxf(s[h], 0.f), wew[h], acc);
  return acc;
}

// One block per (b, i) row: compute ew for all 512 j (2 per thread),
// then row-mean normalize, adjacency mask, softmax -> att row.
__global__ __launch_bounds__(256) void k_att(
    const float* __restrict__ emb, const int* __restrict__ adj,
    const float* __restrict__ Wmap, const float* __restrict__ wew,
    float* __restrict__ att) {
  const int tid = threadIdx.x;
  const size_t rowbase = ((size_t)blockIdx.y * LSEQ + blockIdx.x) * LSEQ;

  const float ew0 = edge_score(emb + ((rowbase + tid) << 6), Wmap, wew);
  const float ew1 = edge_score(emb + ((rowbase + tid + 256) << 6), Wmap, wew);

  __shared__ float redA[4], redB[4], redC[4];
  const int lane = tid & 63, wid = tid >> 6;

  // row mean (mean first, then abs — matches reference)
  float ls = wave_sum64(ew0 + ew1);
  if (lane == 0) redA[wid] = ls;
  __syncthreads();
  const float rmean =
      fabsf((redA[0] + redA[1] + redA[2] + redA[3]) * (1.0f / 512.0f)) + 1e-10f;

  const int a0 = adj[rowbase + tid];
  const int a1 = adj[rowbase + tid + 256];
  const float sc0 = a0 ? (ew0 / rmean) : -9e15f;
  const float sc1 = a1 ? (ew1 / rmean) : -9e15f;

  float lm = wave_max64(fmaxf(sc0, sc1));
  if (lane == 0) redB[wid] = lm;
  __syncthreads();
  const float mx = fmaxf(fmaxf(redB[0], redB[1]), fmaxf(redB[2], redB[3]));

  const float e0 = expf(sc0 - mx);
  const float e1 = expf(sc1 - mx);
  float es = wave_sum64(e0 + e1);
  if (lane == 0) redC[wid] = es;
  __syncthreads();
  const float denom = redC[0] + redC[1] + redC[2] + redC[3];

  att[rowbase + tid] = e0 / denom;
  att[rowbase + tid + 256] = e1 / denom;
}

// h = x @ W_eto + b_eto.  16 rows per block; thread owns column d.
// x accesses are wave-uniform -> s_load; W accesses coalesced across d.
__global__ __launch_bounds__(320) void k_h(
    const float* __restrict__ x, const float* __restrict__ W,
    const float* __restrict__ bias, float* __restrict__ h) {
  const int d = threadIdx.x;
  const int r0 = blockIdx.x << 4;
  if (d >= DDIM) return;
  float acc[16];
  #pragma unroll
  for (int r = 0; r < 16; ++r) acc[r] = 0.f;
  #pragma unroll 4
  for (int k = 0; k < DDIM; ++k) {
    const float wv = W[k * DDIM + d];
    #pragma unroll
    for (int r = 0; r < 16; ++r)
      acc[r] = fmaf(x[(size_t)(r0 + r) * DDIM + k], wv, acc[r]);
  }
  const float bv = bias[d];
  #pragma unroll
  for (int r = 0; r < 16; ++r) h[(size_t)(r0 + r) * DDIM + d] = acc[r] + bv;
}

// h_edge = relu(att @ h).  16 i-rows per block; thread owns column d.
// att accesses wave-uniform -> s_load; h loads coalesced across d.
__global__ __launch_bounds__(320) void k_out(
    const float* __restrict__ att, const float* __restrict__ h,
    float* __restrict__ out) {
  const int d = threadIdx.x;
  const int b = blockIdx.y;
  const int i0 = blockIdx.x << 4;
  if (d >= DDIM) return;
  const float* attB = att + (size_t)b * LSEQ * LSEQ;
  const float* hB = h + (size_t)b * LSEQ * DDIM;
  float acc[16];
  #pragma unroll
  for (int r = 0; r < 16; ++r) acc[r] = 0.f;
  #pragma unroll 4
  for (int k = 0; k < LSEQ; ++k) {
    const float hv = hB[k * DDIM + d];
    #pragma unroll
    for (int r = 0; r < 16; ++r)
      acc[r] = fmaf(attB[(i0 + r) * LSEQ + k], hv, acc[r]);
  }
  #pragma unroll
  for (int r = 0; r < 16; ++r)
    out[((size_t)b * LSEQ + i0 + r) * DDIM + d] = fmaxf(acc[r], 0.f);
}

extern "C" void kernel_launch(void* const* d_in, const int* in_sizes, int n_in,
                              void* d_out, int out_size, void* d_ws, size_t ws_size,
                              hipStream_t stream) {
  const float* x    = (const float*)d_in[0];   // [8,512,300]
  const int*   adj  = (const int*)d_in[1];     // [8,512,512]
  const float* emb  = (const float*)d_in[2];   // [8,512,512,64]
  const float* Wmap = (const float*)d_in[3];   // [64,64]
  const float* wew  = (const float*)d_in[4];   // [64,1]
  const float* Weto = (const float*)d_in[5];   // [300,300]
  const float* beto = (const float*)d_in[6];   // [300]

  float* out    = (float*)d_out;
  float* h_edge = out;                               // [8,512,300]
  float* att    = out + (size_t)8 * LSEQ * DDIM;     // [8,512,512]
  float* h      = (float*)d_ws;                      // [8,512,300] scratch

  // att (dominant kernel, fused ew + normalize + masked softmax)
  k_att<<<dim3(LSEQ, 8), 256, 0, stream>>>(emb, adj, Wmap, wew, att);
  // h = x @ W_eto + b
  k_h<<<dim3((8 * LSEQ) / 16), 320, 0, stream>>>(x, Weto, beto, h);
  // h_edge = relu(att @ h)
  k_out<<<dim3(LSEQ / 16, 8), 320, 0, stream>>>(att, h, h_edge);
}

// Round 3
// 233.548 us; speedup vs baseline: 1.5430x; 1.5430x over previous
//
#include <hip/hip_runtime.h>
#include <hip/hip_bf16.h>

#define LSEQ 512
#define DDIM 300

typedef __attribute__((ext_vector_type(8))) short short8;
typedef __attribute__((ext_vector_type(4))) float f32x4;

__device__ __forceinline__ void split4(f32x4 v, short8& hi, short8& lo, int base) {
  #pragma unroll
  for (int e = 0; e < 4; ++e) {
    const float f = v[e];
    const unsigned b = __float_as_uint(f);
    const float hf = __uint_as_float(b & 0xffff0000u);   // exact bf16-truncation
    hi[base + e] = (short)(b >> 16);
    lo[base + e] = (short)(__float_as_uint(f - hf) >> 16); // remainder, exact in f32
  }
}

// Fused: ew = relu(emb @ W_map) @ w_ew  (split-bf16 MFMA, ~fp32 accuracy)
//        -> row-mean normalize -> adjacency mask -> softmax -> att row.
// One block per (b,i): 4 waves x 8 tiles x 16 edges = 512 edges.
__global__ __launch_bounds__(256) void k_att(
    const float* __restrict__ emb, const int* __restrict__ adj,
    const float* __restrict__ Wmap, const float* __restrict__ wew,
    float* __restrict__ att) {
  __shared__ float ew_lds[LSEQ];
  __shared__ float redA[4], redB[4], redC[4];
  const int tid = threadIdx.x;
  const int lane = tid & 63, wid = tid >> 6;
  const int c = lane & 15, g = lane >> 4;
  const size_t rowbase = ((size_t)blockIdx.y * LSEQ + blockIdx.x) * LSEQ;

  // ---- B fragments: W_map[k][h], k = 32*s + 8*g + e, col = 16*nt + c ----
  short8 bhi[4][2], blo[4][2];
  #pragma unroll
  for (int nt = 0; nt < 4; ++nt) {
    #pragma unroll
    for (int s = 0; s < 2; ++s) {
      #pragma unroll
      for (int e2 = 0; e2 < 2; ++e2) {
        f32x4 w;
        #pragma unroll
        for (int e = 0; e < 4; ++e)
          w[e] = Wmap[(32 * s + 8 * g + 4 * e2 + e) * 64 + 16 * nt + c];
        split4(w, bhi[nt][s], blo[nt][s], 4 * e2);
      }
    }
  }
  float wv[4];
  #pragma unroll
  for (int nt = 0; nt < 4; ++nt) wv[nt] = wew[16 * nt + c];

  // ---- edge-score tiles ----
  for (int it = 0; it < 8; ++it) {
    const int j0 = (wid * 8 + it) * 16;
    // A-frag: row = c (edge j0+c), k = 32*s + 8*g + e
    const float* rowp = emb + ((rowbase + j0 + c) << 6) + 8 * g;
    const f32x4 a0 = *(const f32x4*)(rowp);
    const f32x4 a1 = *(const f32x4*)(rowp + 4);
    const f32x4 a2 = *(const f32x4*)(rowp + 32);
    const f32x4 a3 = *(const f32x4*)(rowp + 36);
    short8 ahi[2], alo[2];
    split4(a0, ahi[0], alo[0], 0);
    split4(a1, ahi[0], alo[0], 4);
    split4(a2, ahi[1], alo[1], 0);
    split4(a3, ahi[1], alo[1], 4);

    f32x4 acc[4];
    #pragma unroll
    for (int nt = 0; nt < 4; ++nt) acc[nt] = (f32x4){0.f, 0.f, 0.f, 0.f};
    #pragma unroll
    for (int s = 0; s < 2; ++s) {
      #pragma unroll
      for (int nt = 0; nt < 4; ++nt) {
        acc[nt] = __builtin_amdgcn_mfma_f32_16x16x32_bf16(ahi[s], bhi[nt][s], acc[nt], 0, 0, 0);
        acc[nt] = __builtin_amdgcn_mfma_f32_16x16x32_bf16(ahi[s], blo[nt][s], acc[nt], 0, 0, 0);
        acc[nt] = __builtin_amdgcn_mfma_f32_16x16x32_bf16(alo[s], bhi[nt][s], acc[nt], 0, 0, 0);
      }
    }
    // epilogue: em -> relu -> x w_ew -> reduce over 16 cols (lanes sharing g)
    // C/D: col = lane&15, row = (lane>>4)*4 + reg  (m89 mapping)
    #pragma unroll
    for (int reg = 0; reg < 4; ++reg) {
      float p = 0.f;
      #pragma unroll
      for (int nt = 0; nt < 4; ++nt)
        p = fmaf(fmaxf(acc[nt][reg], 0.f), wv[nt], p);
      #pragma unroll
      for (int m = 1; m <= 8; m <<= 1) p += __shfl_xor(p, m, 64);
      if (c == 0) ew_lds[j0 + 4 * g + reg] = p;
    }
  }
  __syncthreads();

  // ---- row-mean normalize + masked softmax (identical to passing version) ----
  const float ew0 = ew_lds[tid];
  const float ew1 = ew_lds[tid + 256];

  float ls = ew0 + ew1;
  #pragma unroll
  for (int m = 32; m >= 1; m >>= 1) ls += __shfl_xor(ls, m, 64);
  if (lane == 0) redA[wid] = ls;
  __syncthreads();
  const float rmean =
      fabsf((redA[0] + redA[1] + redA[2] + redA[3]) * (1.0f / 512.0f)) + 1e-10f;

  const int a0i = adj[rowbase + tid];
  const int a1i = adj[rowbase + tid + 256];
  const float sc0 = a0i ? (ew0 / rmean) : -9e15f;
  const float sc1 = a1i ? (ew1 / rmean) : -9e15f;

  float lm = fmaxf(sc0, sc1);
  #pragma unroll
  for (int m = 32; m >= 1; m >>= 1) lm = fmaxf(lm, __shfl_xor(lm, m, 64));
  if (lane == 0) redB[wid] = lm;
  __syncthreads();
  const float mx = fmaxf(fmaxf(redB[0], redB[1]), fmaxf(redB[2], redB[3]));

  const float e0 = expf(sc0 - mx);
  const float e1 = expf(sc1 - mx);
  float es = e0 + e1;
  #pragma unroll
  for (int m = 32; m >= 1; m >>= 1) es += __shfl_xor(es, m, 64);
  if (lane == 0) redC[wid] = es;
  __syncthreads();
  const float denom = redC[0] + redC[1] + redC[2] + redC[3];

  att[rowbase + tid] = e0 / denom;
  att[rowbase + tid + 256] = e1 / denom;
}

// h = x @ W_eto + b_eto.  16 rows per block; thread owns column d.
__global__ __launch_bounds__(320) void k_h(
    const float* __restrict__ x, const float* __restrict__ W,
    const float* __restrict__ bias, float* __restrict__ h) {
  const int d = threadIdx.x;
  const int r0 = blockIdx.x << 4;
  if (d >= DDIM) return;
  float acc[16];
  #pragma unroll
  for (int r = 0; r < 16; ++r) acc[r] = 0.f;
  #pragma unroll 4
  for (int k = 0; k < DDIM; ++k) {
    const float wv = W[k * DDIM + d];
    #pragma unroll
    for (int r = 0; r < 16; ++r)
      acc[r] = fmaf(x[(size_t)(r0 + r) * DDIM + k], wv, acc[r]);
  }
  const float bv = bias[d];
  #pragma unroll
  for (int r = 0; r < 16; ++r) h[(size_t)(r0 + r) * DDIM + d] = acc[r] + bv;
}

// h_edge = relu(att @ h).  16 i-rows per block; thread owns column d.
__global__ __launch_bounds__(320) void k_out(
    const float* __restrict__ att, const float* __restrict__ h,
    float* __restrict__ out) {
  const int d = threadIdx.x;
  const int b = blockIdx.y;
  const int i0 = blockIdx.x << 4;
  if (d >= DDIM) return;
  const float* attB = att + (size_t)b * LSEQ * LSEQ;
  const float* hB = h + (size_t)b * LSEQ * DDIM;
  float acc[16];
  #pragma unroll
  for (int r = 0; r < 16; ++r) acc[r] = 0.f;
  #pragma unroll 4
  for (int k = 0; k < LSEQ; ++k) {
    const float hv = hB[k * DDIM + d];
    #pragma unroll
    for (int r = 0; r < 16; ++r)
      acc[r] = fmaf(attB[(i0 + r) * LSEQ + k], hv, acc[r]);
  }
  #pragma unroll
  for (int r = 0; r < 16; ++r)
    out[((size_t)b * LSEQ + i0 + r) * DDIM + d] = fmaxf(acc[r], 0.f);
}

extern "C" void kernel_launch(void* const* d_in, const int* in_sizes, int n_in,
                              void* d_out, int out_size, void* d_ws, size_t ws_size,
                              hipStream_t stream) {
  const float* x    = (const float*)d_in[0];   // [8,512,300]
  const int*   adj  = (const int*)d_in[1];     // [8,512,512]
  const float* emb  = (const float*)d_in[2];   // [8,512,512,64]
  const float* Wmap = (const float*)d_in[3];   // [64,64]
  const float* wew  = (const float*)d_in[4];   // [64,1]
  const float* Weto = (const float*)d_in[5];   // [300,300]
  const float* beto = (const float*)d_in[6];   // [300]

  float* out    = (float*)d_out;
  float* h_edge = out;                               // [8,512,300]
  float* att    = out + (size_t)8 * LSEQ * DDIM;     // [8,512,512]
  float* h      = (float*)d_ws;                      // [8,512,300] scratch

  k_att<<<dim3(LSEQ, 8), 256, 0, stream>>>(emb, adj, Wmap, wew, att);
  k_h<<<dim3((8 * LSEQ) / 16), 320, 0, stream>>>(x, Weto, beto, h);
  k_out<<<dim3(LSEQ / 16, 8), 320, 0, stream>>>(att, h, h_edge);
}